// Round 12
// baseline (200.923 us; speedup 1.0000x reference)
//
#include <hip/hip_runtime.h>
#include <hip/hip_bf16.h>

typedef __hip_bfloat16 bf16;
typedef short short8v __attribute__((ext_vector_type(8)));
typedef short short4v __attribute__((ext_vector_type(4)));
typedef float floatx4 __attribute__((ext_vector_type(4)));

#define HW 16384

__device__ __forceinline__ float b2f(bf16 v) { return __bfloat162float(v); }
__device__ __forceinline__ bf16 f2b(float v) { return __float2bfloat16(v); }
__device__ __forceinline__ short f2bs(float v) { bf16 h = __float2bfloat16(v); return __builtin_bit_cast(short, h); }
__device__ __forceinline__ float bs2f(short s) { return b2f(__builtin_bit_cast(bf16, s)); }
__device__ __forceinline__ int wuniform(int v) { return __builtin_amdgcn_readfirstlane(v); }

// ---- ws byte offsets (total 41 MiB, proven safe) ----
// xp is 512 KB: [0, 524288). NOTHING else may live below OFFB_K2 (R6 lesson: alias -> NaN).
#define OFFB_XP    0u
#define OFFB_K2    524288u            // after k_attn: bf16 weights (Wproj@0, Wa1@16384, Wa2@20480 shorts)
#define OFFB_V2    786432u
#define OFFB_QKVG  (1u << 20)         // bf16 (b,256,HW): 0-63 q, 64-127 k, 128-191 v, 192-255 qg->res_l
#define OFFB_RESH  (33u << 20)        // bf16 (b,64,HW); first 64KB = conv weights bf16 until k_resh
// p / v-hat scratch in d_out [0,16MiB); d_out fully overwritten by k_proj.

// ---------------- 8x8 avgpool + conv-weight bf16 preconvert (blocks 0-7) ----------------
__global__ __launch_bounds__(256) void k_pool(const float* __restrict__ x, float* __restrict__ xp,
                                              const float* __restrict__ Wqkv, const float* __restrict__ Wq,
                                              short* __restrict__ wconv)
{
    int idx = blockIdx.x * 256 + threadIdx.x;
    int j = idx & 15, i = (idx >> 4) & 15, bc = idx >> 8;
    const float* src = x + (size_t)bc * HW + (i * 8) * 128 + j * 8;
    float s = 0.f;
    #pragma unroll
    for (int u = 0; u < 8; u++) {
        #pragma unroll
        for (int t = 0; t < 8; t++) s += src[u * 128 + t];
    }
    xp[bc * 256 + i * 16 + j] = s * (1.f / 64.f);

    if (blockIdx.x < 8) {               // convert 32768 conv-weight floats -> bf16 (256x128 row-major)
        int base = blockIdx.x * 4096 + threadIdx.x * 16;
        #pragma unroll
        for (int e = 0; e < 16; e += 4) {
            int k = base + e;
            const float* ws = (k < 24576) ? (Wqkv + k) : (Wq + k - 24576);
            floatx4 wv = *(const floatx4*)ws;
            short4v pk;
            pk[0] = f2bs(wv[0]); pk[1] = f2bs(wv[1]); pk[2] = f2bs(wv[2]); pk[3] = f2bs(wv[3]);
            *(short4v*)&wconv[k] = pk;
        }
    }
}

// ---------------- kv conv: xp -> k2/v2 fp32 (b,h,m,d). grid (4b x 128o) = 512 ------------
// R7 fix: one (b,o) per block, Wkv row in LDS, 128 independent coalesced loads.
// Partial-sum order bit-identical to original.
__global__ __launch_bounds__(256) void k_kv(const float* __restrict__ xp,
                                            const float* __restrict__ Wkv, const float* __restrict__ bkv,
                                            float* __restrict__ k2, float* __restrict__ v2)
{
    __shared__ float w_s[128];
    int o = blockIdx.x & 127, b = blockIdx.x >> 7;
    int m = threadIdx.x;
    if (m < 128) w_s[m] = Wkv[o * 128 + m];
    __syncthreads();
    const float* xb = xp + b * 32768 + m;
    float s0 = 0.f, s1 = 0.f, s2 = 0.f, s3 = 0.f;
    #pragma unroll
    for (int c = 0; c < 128; c += 4) {
        s0 += w_s[c]     * xb[(size_t)(c)     * 256];
        s1 += w_s[c + 1] * xb[(size_t)(c + 1) * 256];
        s2 += w_s[c + 2] * xb[(size_t)(c + 2) * 256];
        s3 += w_s[c + 3] * xb[(size_t)(c + 3) * 256];
    }
    float a = bkv[o] + ((s0 + s1) + (s2 + s3));
    int sb = o >> 6, r = o & 63, gh = r >> 4, dh = r & 15;
    float* dst = sb == 0 ? k2 : v2;
    dst[((b * 4 + gh) * 256 + m) * 16 + dh] = a;
}

// ------- MFMA conv1x1: x -> qkvg bf16. grid (128 px-tiles, 4 b); my-loop inside ----------
// R12: x read ONCE (was 2x: both my-blocks loaded the same tile). One block per 128-px
// tile stages B once, then loops my in {0,1} restaging only the 32KB bf16 A panel
// (L2-hot) between barriers. MFMA/epilogue arithmetic bit-identical.
__global__ __launch_bounds__(256) void k_conv(const float* __restrict__ x,
                                              const short* __restrict__ wconv,
                                              const float* __restrict__ bqkv, const float* __restrict__ bq,
                                              bf16* __restrict__ qkvg)
{
    __shared__ short a_s[128 * 128];          // A[oc][k] bf16 (one my panel at a time)
    __shared__ short b_s[128 * 128];          // B packed [k>>3][px][k&7] bf16
    __shared__ float bias_s[256];
    int t = threadIdx.x;
    int b = blockIdx.y;
    int px0 = blockIdx.x * 128;

    bias_s[t] = (t < 192) ? bqkv[t] : bq[t - 192];

    int wave = wuniform(t >> 6);
    int lane = t & 63;
    int quad = lane >> 4, l16 = lane & 15;
    int pxs = t & 127, chalf = (t >> 7) * 64;

    {   // stage B once: 8 coalesced loads -> 1 b128 write, per 8-ch group
        const float* xb = x + (size_t)b * 128 * HW + px0 + pxs;
        #pragma unroll
        for (int p = 0; p < 8; p++) {
            int c0 = chalf + p * 8;
            float xv[8];
            #pragma unroll
            for (int jj = 0; jj < 8; jj++) xv[jj] = xb[(size_t)(c0 + jj) * HW];
            short8v pk;
            #pragma unroll
            for (int jj = 0; jj < 8; jj++) pk[jj] = f2bs(xv[jj]);
            *(short8v*)&b_s[((c0 >> 3) * 128 + pxs) * 8] = pk;
        }
    }

    #pragma unroll 1
    for (int my = 0; my < 2; my++) {
        __syncthreads();                      // my=0: noop-align; my=1: mfma reads of a_s done
        const short* wsrc = wconv + my * 16384;
        #pragma unroll
        for (int i = 0; i < 8; i++) {         // stage A(my): bf16 copy
            int idx = i * 2048 + t * 8;
            *(short8v*)&a_s[idx] = *(const short8v*)&wsrc[idx];
        }
        __syncthreads();                      // a_s (and b_s on my=0) visible

        floatx4 acc[2][8] = {};
        #pragma unroll
        for (int kk = 0; kk < 4; kk++) {
            short8v a0 = *(const short8v*)&a_s[(wave * 32 + l16) * 128 + kk * 32 + quad * 8];
            short8v a1 = *(const short8v*)&a_s[(wave * 32 + 16 + l16) * 128 + kk * 32 + quad * 8];
            #pragma unroll
            for (int nt = 0; nt < 8; nt++) {
                short8v bv = *(const short8v*)&b_s[((kk * 4 + quad) * 128 + nt * 16 + l16) * 8];
                acc[0][nt] = __builtin_amdgcn_mfma_f32_16x16x32_bf16(a0, bv, acc[0][nt], 0, 0, 0);
                acc[1][nt] = __builtin_amdgcn_mfma_f32_16x16x32_bf16(a1, bv, acc[1][nt], 0, 0, 0);
            }
        }
        #pragma unroll
        for (int m = 0; m < 2; m++) {
            int rowb = wave * 32 + m * 16 + quad * 4;
            #pragma unroll
            for (int nt = 0; nt < 8; nt++) {
                int px = px0 + nt * 16 + l16;
                #pragma unroll
                for (int r = 0; r < 4; r++) {
                    int row = rowb + r;
                    float val = acc[m][nt][r] + bias_s[my * 128 + row];
                    qkvg[((size_t)b * 256 + my * 128 + row) * HW + px] = f2b(val);
                }
            }
        }
    }
}

// ---------------- depthwise 3x3 + q*k, vectorized: 8 px/thread. grid 2048 ----------------
__global__ __launch_bounds__(256) void k_dw(const bf16* __restrict__ qkvg,
                                            const float* __restrict__ Wdw, const float* __restrict__ bdw,
                                            bf16* __restrict__ p, bf16* __restrict__ v)
{
    int blk = blockIdx.x;            // 2048
    int bc = blk >> 3;               // b*64+c
    int c = bc & 63, b = bc >> 6;
    int g = (blk & 7) * 256 + threadIdx.x;   // 0..2047 pixel-groups in plane
    int i = g >> 4;                  // row
    int j0 = (g & 15) * 8;           // col start
    float acc[3][8];
    #pragma unroll
    for (int pl = 0; pl < 3; pl++) {
        float bias = bdw[pl * 64 + c];
        #pragma unroll
        for (int t2 = 0; t2 < 8; t2++) acc[pl][t2] = bias;
    }
    #pragma unroll
    for (int pl = 0; pl < 3; pl++) {
        const bf16* plane = qkvg + (size_t)(b * 256 + pl * 64 + c) * HW;
        const float* w = Wdw + (pl * 64 + c) * 9;
        #pragma unroll
        for (int dy = 0; dy < 3; dy++) {
            int ii = i + dy - 1;
            float e[10];
            if ((unsigned)ii < 128u) {
                const bf16* r = plane + ii * 128 + j0;
                short8v v8 = *(const short8v*)r;
                #pragma unroll
                for (int t2 = 0; t2 < 8; t2++) e[t2 + 1] = bs2f(v8[t2]);
                e[0] = (j0 > 0) ? b2f(r[-1]) : 0.f;
                e[9] = (j0 < 120) ? b2f(r[8]) : 0.f;
            } else {
                #pragma unroll
                for (int t2 = 0; t2 < 10; t2++) e[t2] = 0.f;
            }
            float wa = w[dy * 3], wb = w[dy * 3 + 1], wc = w[dy * 3 + 2];
            #pragma unroll
            for (int t2 = 0; t2 < 8; t2++)
                acc[pl][t2] += wa * e[t2] + wb * e[t2 + 1] + wc * e[t2 + 2];
        }
    }
    short8v pv, vv;
    #pragma unroll
    for (int t2 = 0; t2 < 8; t2++) {
        pv[t2] = f2bs(acc[0][t2] * acc[1][t2]);
        vv[t2] = f2bs(acc[2][t2]);
    }
    size_t off = (size_t)(b * 64 + c) * HW + i * 128 + j0;
    *(short8v*)(p + off) = pv;
    *(short8v*)(v + off) = vv;
}

// ---------------- MFMA low-freq attention. grid (256 px-blocks, 4 h, 4 b), 256 thr ------
// In-register P (proven R4). R12: Q staging LDS round-trip removed -- in the 1-pxt-per-
// wave layout thread t's staged frag was read back by the SAME thread (identity), so qf
// is computed directly into registers. LDS 24 KiB (kt+vt) -> 6 blocks/CU. Bit-identical.
__global__ __launch_bounds__(256, 6) void k_attn(bf16* __restrict__ qkvg, const float* __restrict__ k2,
                                                 const float* __restrict__ v2)
{
    __shared__ short kt[16 * 64 * 8];   // 16 KiB: K A-frags (key-permuted), k=16..31 zero
    __shared__ short vt[8 * 64 * 8];    // 8 KiB: V frags (A-role: V^T)
    int t = threadIdx.x;
    int h = blockIdx.y, b = blockIdx.z;
    int px0b = blockIdx.x * 64;
    const float* K = k2 + (size_t)(b * 4 + h) * 4096;
    const float* V = v2 + (size_t)(b * 4 + h) * 4096;
    bf16* Qbase = qkvg + (size_t)(b * 256 + 192 + h * 16) * HW + px0b;

    {
        int mb = t >> 5, kl = t & 31, q = kl >> 3, s = kl & 7;
        int tile = 2 * mb + (s >> 2), row = q * 4 + (s & 3);
        float4 k0 = *(const float4*)(K + t * 16);
        float4 k1 = *(const float4*)(K + t * 16 + 4);
        float4 kx2 = *(const float4*)(K + t * 16 + 8);
        float4 k3 = *(const float4*)(K + t * 16 + 12);
        short8v lo, hi, zz = {};
        lo[0] = f2bs(k0.x); lo[1] = f2bs(k0.y); lo[2] = f2bs(k0.z); lo[3] = f2bs(k0.w);
        lo[4] = f2bs(k1.x); lo[5] = f2bs(k1.y); lo[6] = f2bs(k1.z); lo[7] = f2bs(k1.w);
        hi[0] = f2bs(kx2.x); hi[1] = f2bs(kx2.y); hi[2] = f2bs(kx2.z); hi[3] = f2bs(kx2.w);
        hi[4] = f2bs(k3.x); hi[5] = f2bs(k3.y); hi[6] = f2bs(k3.z); hi[7] = f2bs(k3.w);
        *(short8v*)&kt[(tile * 64 + row) * 8] = lo;
        *(short8v*)&kt[(tile * 64 + 16 + row) * 8] = hi;
        *(short8v*)&kt[(tile * 64 + 32 + row) * 8] = zz;
        *(short8v*)&kt[(tile * 64 + 48 + row) * 8] = zz;
    }
    #pragma unroll
    for (int u = 0; u < 2; u++) {           // 512 V frags, two per thread
        int f = t * 2 + u;
        int mb = f >> 6, lane = f & 63, quad = lane >> 4, d = lane & 15;
        short8v pk;
        #pragma unroll
        for (int i = 0; i < 8; i++) pk[i] = f2bs(V[(mb * 32 + quad * 8 + i) * 16 + d]);
        *(short8v*)&vt[f * 8] = pk;
    }

    int wave = wuniform(t >> 6);            // 0..3, = this wave's pxt
    int lane = t & 63;
    int quad = lane >> 4, l16 = lane & 15;
    short8v qf = {};
    if (quad < 2) {                         // Q B-frag directly in registers (no LDS)
        int px = wave * 16 + l16;
        #pragma unroll
        for (int i = 0; i < 8; i++)         // 0.25 (= dh^-0.5) * log2(e) folded in
            qf[i] = f2bs(b2f(Qbase[(size_t)(quad * 8 + i) * HW + px]) * 0.36067376022224085f);
    }
    __syncthreads();

    {
        int pxt = wave;
        floatx4 denv = {};
        floatx4 oa = {};
        #pragma unroll
        for (int mb = 0; mb < 8; mb++) {
            short8v kfE = *(const short8v*)&kt[((2 * mb) * 64 + lane) * 8];
            short8v kfO = *(const short8v*)&kt[((2 * mb + 1) * 64 + lane) * 8];
            floatx4 scE = __builtin_amdgcn_mfma_f32_16x16x32_bf16(kfE, qf, (floatx4){0.f, 0.f, 0.f, 0.f}, 0, 0, 0);
            floatx4 scO = __builtin_amdgcn_mfma_f32_16x16x32_bf16(kfO, qf, (floatx4){0.f, 0.f, 0.f, 0.f}, 0, 0, 0);
            floatx4 peE, peO;
            #pragma unroll
            for (int r = 0; r < 4; r++) {
                peE[r] = exp2f(fminf(scE[r], 86.f));
                peO[r] = exp2f(fminf(scO[r], 86.f));
            }
            denv += peE;
            denv += peO;
            short8v pa;
            pa[0] = f2bs(peE[0]); pa[1] = f2bs(peE[1]); pa[2] = f2bs(peE[2]); pa[3] = f2bs(peE[3]);
            pa[4] = f2bs(peO[0]); pa[5] = f2bs(peO[1]); pa[6] = f2bs(peO[2]); pa[7] = f2bs(peO[3]);
            short8v vf = *(const short8v*)&vt[(mb * 64 + lane) * 8];
            oa = __builtin_amdgcn_mfma_f32_16x16x32_bf16(vf, pa, oa, 0, 0, 0);
        }
        float den = (denv[0] + denv[1]) + (denv[2] + denv[3]);
        den += __shfl_xor(den, 16, 64);
        den += __shfl_xor(den, 32, 64);
        float rden = 1.f / den;
        #pragma unroll
        for (int r = 0; r < 4; r++)
            Qbase[(size_t)(quad * 4 + r) * HW + pxt * 16 + l16] = f2b(oa[r] * rden);
    }
}

// ---------------- late-weight bf16 preconvert: Wproj/Wa1/Wa2 -> k2 region (dead) ---------
__global__ __launch_bounds__(256) void k_wcvt(const float* __restrict__ Wproj,
                                              const float* __restrict__ Wa1, const float* __restrict__ Wa2,
                                              short* __restrict__ wdst)
{
    int idx = blockIdx.x * 1024 + threadIdx.x * 4;   // 24 blocks -> 24576 floats
    const float* src;
    if (idx < 16384)      src = Wproj + idx;
    else if (idx < 20480) src = Wa1 + (idx - 16384);
    else                  src = Wa2 + (idx - 20480);
    floatx4 wv = *(const floatx4*)src;
    short4v pk;
    pk[0] = f2bs(wv[0]); pk[1] = f2bs(wv[1]); pk[2] = f2bs(wv[2]); pk[3] = f2bs(wv[3]);
    *(short4v*)&wdst[idx] = pk;
}

// ---------------- MFMA high-freq gate: p,v-hat -> res_h. grid (128 px-tiles, 4 b) --------
// GEMM1 (Wa1 64x64 · P) -> swish -> repack -> GEMM2 (Wa2 64x64) -> tanh*vhat
// bp staging conflict-free: per-thread px, 8-channel gather -> 1 b128 write.
__global__ __launch_bounds__(256) void k_resh(const bf16* __restrict__ p, const bf16* __restrict__ vhat,
                                              const short* __restrict__ wabf,
                                              const float* __restrict__ ba1, const float* __restrict__ ba2,
                                              bf16* __restrict__ resh)
{
    __shared__ short aw1[64 * 64];       // A1[oc][ic]
    __shared__ short aw2[64 * 64];       // A2[oc][ic]
    __shared__ short bp[8 * 128 * 8];    // P  packed [ic>>3][px][ic&7]
    __shared__ short bs2[8 * 128 * 8];   // swish packed (same layout)
    __shared__ float b1s[64], b2s[64];
    int t = threadIdx.x;
    int b = blockIdx.y;
    int px0 = blockIdx.x * 128;

    if (t < 64) { b1s[t] = ba1[t]; b2s[t] = ba2[t]; }
    #pragma unroll
    for (int i = 0; i < 2; i++) {        // stage Wa1/Wa2 (bf16 pre-converted)
        int idx = i * 2048 + t * 8;
        *(short8v*)&aw1[idx] = *(const short8v*)&wabf[idx];
        *(short8v*)&aw2[idx] = *(const short8v*)&wabf[4096 + idx];
    }
    {
        int pxs = t & 127, chalf = (t >> 7) * 32;
        const short* pb = (const short*)p + (size_t)b * 64 * HW + px0 + pxs;
        #pragma unroll
        for (int pp = 0; pp < 4; pp++) {  // stage P: 8-channel gather -> b128 write
            int c0 = chalf + pp * 8;
            short8v pk;
            #pragma unroll
            for (int jj = 0; jj < 8; jj++) pk[jj] = pb[(size_t)(c0 + jj) * HW];
            *(short8v*)&bp[((c0 >> 3) * 128 + pxs) * 8] = pk;
        }
    }
    __syncthreads();

    int wave = wuniform(t >> 6);         // = mtile (M=64 -> 4 mtiles)
    int lane = t & 63;
    int quad = lane >> 4, l16 = lane & 15;
    int k0 = wave * 16 + quad * 4;       // output-channel base for this lane's C rows

    floatx4 acc1[8] = {};
    #pragma unroll
    for (int kk = 0; kk < 2; kk++) {
        short8v af = *(const short8v*)&aw1[(wave * 16 + l16) * 64 + kk * 32 + quad * 8];
        #pragma unroll
        for (int nt = 0; nt < 8; nt++) {
            short8v bf = *(const short8v*)&bp[((kk * 4 + quad) * 128 + nt * 16 + l16) * 8];
            acc1[nt] = __builtin_amdgcn_mfma_f32_16x16x32_bf16(af, bf, acc1[nt], 0, 0, 0);
        }
    }
    #pragma unroll
    for (int nt = 0; nt < 8; nt++) {     // swish + repack C-layout -> B-frag layout
        int px = nt * 16 + l16;
        short4v pk;
        #pragma unroll
        for (int r = 0; r < 4; r++) {
            float a = acc1[nt][r] + b1s[k0 + r];
            pk[r] = f2bs(a / (1.f + __expf(-a)));
        }
        *(short4v*)&bs2[((k0 >> 3) * 128 + px) * 8 + (k0 & 7)] = pk;
    }
    __syncthreads();

    floatx4 acc2[8] = {};
    #pragma unroll
    for (int kk = 0; kk < 2; kk++) {
        short8v af = *(const short8v*)&aw2[(wave * 16 + l16) * 64 + kk * 32 + quad * 8];
        #pragma unroll
        for (int nt = 0; nt < 8; nt++) {
            short8v bf = *(const short8v*)&bs2[((kk * 4 + quad) * 128 + nt * 16 + l16) * 8];
            acc2[nt] = __builtin_amdgcn_mfma_f32_16x16x32_bf16(af, bf, acc2[nt], 0, 0, 0);
        }
    }
    #pragma unroll
    for (int nt = 0; nt < 8; nt++) {
        int px = px0 + nt * 16 + l16;
        #pragma unroll
        for (int r = 0; r < 4; r++) {
            int oc = k0 + r;
            float g = tanhf((acc2[nt][r] + b2s[oc]) * 0.25f);
            float vv = b2f(vhat[(size_t)(b * 64 + oc) * HW + px]);
            resh[(size_t)(b * 64 + oc) * HW + px] = f2b(g * vv);
        }
    }
}

// ---------------- MFMA final proj: [res_h|res_l] -> out fp32. grid (128 px-tiles, 4 b) ---
// B staging conflict-free: per-thread px, 8-channel gather -> 1 b128 write.
__global__ __launch_bounds__(256) void k_proj(const bf16* __restrict__ resh, const bf16* __restrict__ qkvg,
                                              const short* __restrict__ wpbf, const float* __restrict__ bproj,
                                              float* __restrict__ out)
{
    __shared__ short a_s[128 * 128];
    __shared__ short b_s[128 * 128];
    __shared__ float bias_s[128];
    int t = threadIdx.x;
    int b = blockIdx.y;
    int px0 = blockIdx.x * 128;
    const bf16* resl = qkvg + (size_t)(b * 256 + 192) * HW;

    if (t < 128) bias_s[t] = bproj[t];
    #pragma unroll
    for (int i = 0; i < 8; i++) {        // stage A (Wproj bf16 pre-converted)
        int idx = i * 2048 + t * 8;
        *(short8v*)&a_s[idx] = *(const short8v*)&wpbf[idx];
    }
    {
        int pxs = t & 127, half = t >> 7;
        const short* srcb = half == 0 ? ((const short*)resh + (size_t)b * 64 * HW + px0 + pxs)
                                      : ((const short*)resl + px0 + pxs);
        #pragma unroll
        for (int pp = 0; pp < 8; pp++) {  // stage B: 8-channel gather -> b128 write
            int c0 = half * 64 + pp * 8;
            short8v pk;
            #pragma unroll
            for (int jj = 0; jj < 8; jj++) pk[jj] = srcb[(size_t)(pp * 8 + jj) * HW];
            *(short8v*)&b_s[((c0 >> 3) * 128 + pxs) * 8] = pk;
        }
    }
    __syncthreads();

    int wave = wuniform(t >> 6);
    int lane = t & 63;
    int quad = lane >> 4, l16 = lane & 15;
    floatx4 acc[2][8] = {};
    #pragma unroll
    for (int kk = 0; kk < 4; kk++) {
        short8v a0 = *(const short8v*)&a_s[(wave * 32 + l16) * 128 + kk * 32 + quad * 8];
        short8v a1 = *(const short8v*)&a_s[(wave * 32 + 16 + l16) * 128 + kk * 32 + quad * 8];
        #pragma unroll
        for (int nt = 0; nt < 8; nt++) {
            short8v bv = *(const short8v*)&b_s[((kk * 4 + quad) * 128 + nt * 16 + l16) * 8];
            acc[0][nt] = __builtin_amdgcn_mfma_f32_16x16x32_bf16(a0, bv, acc[0][nt], 0, 0, 0);
            acc[1][nt] = __builtin_amdgcn_mfma_f32_16x16x32_bf16(a1, bv, acc[1][nt], 0, 0, 0);
        }
    }
    #pragma unroll
    for (int m = 0; m < 2; m++) {
        int rowb = wave * 32 + m * 16 + quad * 4;
        #pragma unroll
        for (int nt = 0; nt < 8; nt++) {
            int px = px0 + nt * 16 + l16;
            #pragma unroll
            for (int r = 0; r < 4; r++) {
                int row = rowb + r;
                out[((size_t)b * 128 + row) * HW + px] = acc[m][nt][r] + bias_s[row];
            }
        }
    }
}

extern "C" void kernel_launch(void* const* d_in, const int* in_sizes, int n_in,
                              void* d_out, int out_size, void* d_ws, size_t ws_size,
                              hipStream_t stream)
{
    (void)in_sizes; (void)n_in; (void)out_size; (void)ws_size;
    const float* x     = (const float*)d_in[0];
    const float* Wqkv  = (const float*)d_in[1];
    const float* bqkv  = (const float*)d_in[2];
    const float* Wdw   = (const float*)d_in[3];
    const float* bdw   = (const float*)d_in[4];
    const float* Wa1   = (const float*)d_in[5];
    const float* ba1   = (const float*)d_in[6];
    const float* Wa2   = (const float*)d_in[7];
    const float* ba2   = (const float*)d_in[8];
    const float* Wq    = (const float*)d_in[9];
    const float* bq    = (const float*)d_in[10];
    const float* Wkv   = (const float*)d_in[11];
    const float* bkv   = (const float*)d_in[12];
    const float* Wproj = (const float*)d_in[13];
    const float* bproj = (const float*)d_in[14];

    char* wsb = (char*)d_ws;
    float* xp   = (float*)(wsb + OFFB_XP);
    float* k2   = (float*)(wsb + OFFB_K2);
    float* v2   = (float*)(wsb + OFFB_V2);
    bf16*  qkvg = (bf16*)(wsb + OFFB_QKVG);
    bf16*  resh = (bf16*)(wsb + OFFB_RESH);
    short* wconv = (short*)(wsb + OFFB_RESH); // conv weights bf16; dead before k_resh writes
    short* wlate = (short*)(wsb + OFFB_K2);   // Wproj/Wa bf16; k2 dead after k_attn
    bf16*  p    = (bf16*)d_out;               // scratch in d_out, dead before k_proj
    bf16*  v    = (bf16*)d_out + 4194304;
    float* out  = (float*)d_out;

    k_pool<<<dim3(512), 256, 0, stream>>>(x, xp, Wqkv, Wq, wconv);
    k_kv<<<dim3(512), 256, 0, stream>>>(xp, Wkv, bkv, k2, v2);
    k_conv<<<dim3(128, 4), 256, 0, stream>>>(x, wconv, bqkv, bq, qkvg);
    k_dw<<<dim3(2048), 256, 0, stream>>>(qkvg, Wdw, bdw, p, v);
    k_attn<<<dim3(256, 4, 4), 256, 0, stream>>>(qkvg, k2, v2);      // res_l in-place over qg ch
    k_wcvt<<<dim3(24), 256, 0, stream>>>(Wproj, Wa1, Wa2, wlate);
    k_resh<<<dim3(128, 4), 256, 0, stream>>>(p, v, wlate + 16384, ba1, ba2, resh);
    k_proj<<<dim3(128, 4), 256, 0, stream>>>(resh, qkvg, wlate, bproj, out);
}

// Round 13
// 193.322 us; speedup vs baseline: 1.0393x; 1.0393x over previous
//
#include <hip/hip_runtime.h>
#include <hip/hip_bf16.h>

typedef __hip_bfloat16 bf16;
typedef short short8v __attribute__((ext_vector_type(8)));
typedef short short4v __attribute__((ext_vector_type(4)));
typedef float floatx4 __attribute__((ext_vector_type(4)));

#define HW 16384

__device__ __forceinline__ float b2f(bf16 v) { return __bfloat162float(v); }
__device__ __forceinline__ bf16 f2b(float v) { return __float2bfloat16(v); }
__device__ __forceinline__ short f2bs(float v) { bf16 h = __float2bfloat16(v); return __builtin_bit_cast(short, h); }
__device__ __forceinline__ float bs2f(short s) { return b2f(__builtin_bit_cast(bf16, s)); }
__device__ __forceinline__ int wuniform(int v) { return __builtin_amdgcn_readfirstlane(v); }

// ---- ws byte offsets (total 41 MiB, proven safe) ----
// xp is 512 KB: [0, 524288). NOTHING else below OFFB_K2 (R6 lesson: alias -> NaN).
// R13: no weight-preconvert buffers (in-kernel fp32->bf16 staging, R4-proven, R5-neutral).
#define OFFB_XP    0u
#define OFFB_K2    524288u
#define OFFB_V2    786432u
#define OFFB_QKVG  (1u << 20)         // bf16 (b,256,HW): 0-63 q, 64-127 k, 128-191 v, 192-255 qg->res_l
#define OFFB_RESH  (33u << 20)        // bf16 (b,64,HW)
// p / v-hat scratch in d_out [0,16MiB); d_out fully overwritten by k_proj.

// ======== Launch A: conv1x1 (blocks 0..511) + 8x8 avgpool (blocks 512..1023) ============
// Independent: both read only x; write qkvg / xp respectively.
__global__ __launch_bounds__(256) void k_fuseA(const float* __restrict__ x,
                                               const float* __restrict__ Wqkv, const float* __restrict__ bqkv,
                                               const float* __restrict__ Wq,  const float* __restrict__ bq,
                                               bf16* __restrict__ qkvg, float* __restrict__ xp)
{
    __shared__ __align__(16) char smem[66560];   // conv: a_s 32K | b_s 32K | bias 1K
    int t = threadIdx.x;
    int bid = blockIdx.x;

    if (bid < 512) {
        // ---- conv1x1: x -> qkvg. R12 body (B staged once, my-loop restages A) ----
        short* a_s = (short*)smem;
        short* b_s = (short*)(smem + 32768);
        float* bias_s = (float*)(smem + 65536);
        int b = bid >> 7;
        int px0 = (bid & 127) * 128;

        bias_s[t] = (t < 192) ? bqkv[t] : bq[t - 192];

        int wave = wuniform(t >> 6);
        int lane = t & 63;
        int quad = lane >> 4, l16 = lane & 15;
        int pxs = t & 127, chalf = (t >> 7) * 64;

        {   // stage B once: 8 coalesced loads -> 1 b128 write per 8-ch group
            const float* xb = x + (size_t)b * 128 * HW + px0 + pxs;
            #pragma unroll
            for (int p = 0; p < 8; p++) {
                int c0 = chalf + p * 8;
                float xv[8];
                #pragma unroll
                for (int jj = 0; jj < 8; jj++) xv[jj] = xb[(size_t)(c0 + jj) * HW];
                short8v pk;
                #pragma unroll
                for (int jj = 0; jj < 8; jj++) pk[jj] = f2bs(xv[jj]);
                *(short8v*)&b_s[((c0 >> 3) * 128 + pxs) * 8] = pk;
            }
        }

        #pragma unroll 1
        for (int my = 0; my < 2; my++) {
            __syncthreads();                  // my=1: mfma reads of a_s done
            #pragma unroll
            for (int i = 0; i < 16; i++) {    // stage A(my): fp32 -> bf16 (R4-proven path)
                int idx = i * 1024 + t * 4;
                int row = idx >> 7, col = idx & 127;
                int oc = my * 128 + row;
                const float* srcw = (oc < 192) ? (Wqkv + oc * 128 + col) : (Wq + (oc - 192) * 128 + col);
                floatx4 wv = *(const floatx4*)srcw;
                short4v pk4;
                pk4[0] = f2bs(wv[0]); pk4[1] = f2bs(wv[1]); pk4[2] = f2bs(wv[2]); pk4[3] = f2bs(wv[3]);
                *(short4v*)&a_s[row * 128 + col] = pk4;
            }
            __syncthreads();                  // a_s (and b_s on my=0) visible

            floatx4 acc[2][8] = {};
            #pragma unroll
            for (int kk = 0; kk < 4; kk++) {
                short8v a0 = *(const short8v*)&a_s[(wave * 32 + l16) * 128 + kk * 32 + quad * 8];
                short8v a1 = *(const short8v*)&a_s[(wave * 32 + 16 + l16) * 128 + kk * 32 + quad * 8];
                #pragma unroll
                for (int nt = 0; nt < 8; nt++) {
                    short8v bv = *(const short8v*)&b_s[((kk * 4 + quad) * 128 + nt * 16 + l16) * 8];
                    acc[0][nt] = __builtin_amdgcn_mfma_f32_16x16x32_bf16(a0, bv, acc[0][nt], 0, 0, 0);
                    acc[1][nt] = __builtin_amdgcn_mfma_f32_16x16x32_bf16(a1, bv, acc[1][nt], 0, 0, 0);
                }
            }
            #pragma unroll
            for (int m = 0; m < 2; m++) {
                int rowb = wave * 32 + m * 16 + quad * 4;
                #pragma unroll
                for (int nt = 0; nt < 8; nt++) {
                    int px = px0 + nt * 16 + l16;
                    #pragma unroll
                    for (int r = 0; r < 4; r++) {
                        int row = rowb + r;
                        float val = acc[m][nt][r] + bias_s[my * 128 + row];
                        qkvg[((size_t)b * 256 + my * 128 + row) * HW + px] = f2b(val);
                    }
                }
            }
        }
    } else {
        // ---- 8x8 avgpool: x -> xp ----
        int idx = (bid - 512) * 256 + t;
        int j = idx & 15, i = (idx >> 4) & 15, bc = idx >> 8;
        const float* src = x + (size_t)bc * HW + (i * 8) * 128 + j * 8;
        float s = 0.f;
        #pragma unroll
        for (int u = 0; u < 8; u++) {
            #pragma unroll
            for (int t2 = 0; t2 < 8; t2++) s += src[u * 128 + t2];
        }
        xp[bc * 256 + i * 16 + j] = s * (1.f / 64.f);
    }
}

// ======== Launch B: kv conv (blocks 0..511) + depthwise 3x3 (blocks 512..2559) ==========
// Independent: kv reads xp -> k2/v2; dw reads qkvg -> p/v. Disjoint writes.
__global__ __launch_bounds__(256) void k_fuseB(const float* __restrict__ xp,
                                               const float* __restrict__ Wkv, const float* __restrict__ bkv,
                                               float* __restrict__ k2, float* __restrict__ v2,
                                               const bf16* __restrict__ qkvg,
                                               const float* __restrict__ Wdw, const float* __restrict__ bdw,
                                               bf16* __restrict__ p, bf16* __restrict__ v)
{
    __shared__ float w_s[128];
    int t = threadIdx.x;
    int bid = blockIdx.x;

    if (bid < 512) {
        // ---- kv conv (R7-proven): one (b,o) per block ----
        int o = bid & 127, b = bid >> 7;
        int m = t;
        if (m < 128) w_s[m] = Wkv[o * 128 + m];
        __syncthreads();
        const float* xb = xp + b * 32768 + m;
        float s0 = 0.f, s1 = 0.f, s2 = 0.f, s3 = 0.f;
        #pragma unroll
        for (int c = 0; c < 128; c += 4) {
            s0 += w_s[c]     * xb[(size_t)(c)     * 256];
            s1 += w_s[c + 1] * xb[(size_t)(c + 1) * 256];
            s2 += w_s[c + 2] * xb[(size_t)(c + 2) * 256];
            s3 += w_s[c + 3] * xb[(size_t)(c + 3) * 256];
        }
        float a = bkv[o] + ((s0 + s1) + (s2 + s3));
        int sb = o >> 6, r = o & 63, gh = r >> 4, dh = r & 15;
        float* dst = sb == 0 ? k2 : v2;
        dst[((b * 4 + gh) * 256 + m) * 16 + dh] = a;
    } else {
        // ---- depthwise 3x3 + q*k (proven body), blk = bid-512 ----
        int blk = bid - 512;
        int bc = blk >> 3;
        int c = bc & 63, b = bc >> 6;
        int g = (blk & 7) * 256 + t;
        int i = g >> 4;
        int j0 = (g & 15) * 8;
        float acc[3][8];
        #pragma unroll
        for (int pl = 0; pl < 3; pl++) {
            float bias = bdw[pl * 64 + c];
            #pragma unroll
            for (int t2 = 0; t2 < 8; t2++) acc[pl][t2] = bias;
        }
        #pragma unroll
        for (int pl = 0; pl < 3; pl++) {
            const bf16* plane = qkvg + (size_t)(b * 256 + pl * 64 + c) * HW;
            const float* w = Wdw + (pl * 64 + c) * 9;
            #pragma unroll
            for (int dy = 0; dy < 3; dy++) {
                int ii = i + dy - 1;
                float e[10];
                if ((unsigned)ii < 128u) {
                    const bf16* r = plane + ii * 128 + j0;
                    short8v v8 = *(const short8v*)r;
                    #pragma unroll
                    for (int t2 = 0; t2 < 8; t2++) e[t2 + 1] = bs2f(v8[t2]);
                    e[0] = (j0 > 0) ? b2f(r[-1]) : 0.f;
                    e[9] = (j0 < 120) ? b2f(r[8]) : 0.f;
                } else {
                    #pragma unroll
                    for (int t2 = 0; t2 < 10; t2++) e[t2] = 0.f;
                }
                float wa = w[dy * 3], wb = w[dy * 3 + 1], wc = w[dy * 3 + 2];
                #pragma unroll
                for (int t2 = 0; t2 < 8; t2++)
                    acc[pl][t2] += wa * e[t2] + wb * e[t2 + 1] + wc * e[t2 + 2];
            }
        }
        short8v pv, vv;
        #pragma unroll
        for (int t2 = 0; t2 < 8; t2++) {
            pv[t2] = f2bs(acc[0][t2] * acc[1][t2]);
            vv[t2] = f2bs(acc[2][t2]);
        }
        size_t off = (size_t)(b * 64 + c) * HW + i * 128 + j0;
        *(short8v*)(p + off) = pv;
        *(short8v*)(v + off) = vv;
    }
}

// ======== Launch C: high-freq gate (blocks 0..511) + attention (blocks 512..4607) =======
// Independent: resh reads p/v -> resh buf; attn reads qg/k2/v2 -> qg in-place.
__global__ __launch_bounds__(256) void k_fuseC(bf16* __restrict__ qkvg,
                                               const float* __restrict__ k2, const float* __restrict__ v2,
                                               const bf16* __restrict__ p, const bf16* __restrict__ vhat,
                                               const float* __restrict__ Wa1, const float* __restrict__ ba1,
                                               const float* __restrict__ Wa2, const float* __restrict__ ba2,
                                               bf16* __restrict__ resh)
{
    __shared__ __align__(16) char smem[49664];  // resh: 48.5K | attn: 24K
    int t = threadIdx.x;
    int bid = blockIdx.x;

    if (bid < 512) {
        // ---- high-freq gate (proven body; Wa staged fp32->bf16, R4 path) ----
        short* aw1 = (short*)smem;                    // 64*64
        short* aw2 = (short*)(smem + 8192);           // 64*64
        short* bp  = (short*)(smem + 16384);          // 8*128*8
        short* bs2 = (short*)(smem + 32768);          // 8*128*8
        float* b1s = (float*)(smem + 49152);          // 64
        float* b2s = (float*)(smem + 49408);          // 64
        int b = bid >> 7;
        int px0 = (bid & 127) * 128;

        if (t < 64) { b1s[t] = ba1[t]; b2s[t] = ba2[t]; }
        #pragma unroll
        for (int i = 0; i < 4; i++) {        // stage Wa1/Wa2 fp32->bf16 (4096 each)
            int idx = i * 1024 + t * 4;
            floatx4 w1 = *(const floatx4*)(Wa1 + idx);
            floatx4 w2 = *(const floatx4*)(Wa2 + idx);
            short4v p1, p2;
            #pragma unroll
            for (int e = 0; e < 4; e++) { p1[e] = f2bs(w1[e]); p2[e] = f2bs(w2[e]); }
            *(short4v*)&aw1[idx] = p1;
            *(short4v*)&aw2[idx] = p2;
        }
        {
            int pxs = t & 127, chalf = (t >> 7) * 32;
            const short* pb = (const short*)p + (size_t)b * 64 * HW + px0 + pxs;
            #pragma unroll
            for (int pp = 0; pp < 4; pp++) {  // stage P: 8-channel gather -> b128 write
                int c0 = chalf + pp * 8;
                short8v pk;
                #pragma unroll
                for (int jj = 0; jj < 8; jj++) pk[jj] = pb[(size_t)(c0 + jj) * HW];
                *(short8v*)&bp[((c0 >> 3) * 128 + pxs) * 8] = pk;
            }
        }
        __syncthreads();

        int wave = wuniform(t >> 6);
        int lane = t & 63;
        int quad = lane >> 4, l16 = lane & 15;
        int k0 = wave * 16 + quad * 4;

        floatx4 acc1[8] = {};
        #pragma unroll
        for (int kk = 0; kk < 2; kk++) {
            short8v af = *(const short8v*)&aw1[(wave * 16 + l16) * 64 + kk * 32 + quad * 8];
            #pragma unroll
            for (int nt = 0; nt < 8; nt++) {
                short8v bf = *(const short8v*)&bp[((kk * 4 + quad) * 128 + nt * 16 + l16) * 8];
                acc1[nt] = __builtin_amdgcn_mfma_f32_16x16x32_bf16(af, bf, acc1[nt], 0, 0, 0);
            }
        }
        #pragma unroll
        for (int nt = 0; nt < 8; nt++) {     // swish + repack C-layout -> B-frag layout
            int px = nt * 16 + l16;
            short4v pk;
            #pragma unroll
            for (int r = 0; r < 4; r++) {
                float a = acc1[nt][r] + b1s[k0 + r];
                pk[r] = f2bs(a / (1.f + __expf(-a)));
            }
            *(short4v*)&bs2[((k0 >> 3) * 128 + px) * 8 + (k0 & 7)] = pk;
        }
        __syncthreads();

        floatx4 acc2[8] = {};
        #pragma unroll
        for (int kk = 0; kk < 2; kk++) {
            short8v af = *(const short8v*)&aw2[(wave * 16 + l16) * 64 + kk * 32 + quad * 8];
            #pragma unroll
            for (int nt = 0; nt < 8; nt++) {
                short8v bf = *(const short8v*)&bs2[((kk * 4 + quad) * 128 + nt * 16 + l16) * 8];
                acc2[nt] = __builtin_amdgcn_mfma_f32_16x16x32_bf16(af, bf, acc2[nt], 0, 0, 0);
            }
        }
        #pragma unroll
        for (int nt = 0; nt < 8; nt++) {
            int px = px0 + nt * 16 + l16;
            #pragma unroll
            for (int r = 0; r < 4; r++) {
                int oc = k0 + r;
                float g = tanhf((acc2[nt][r] + b2s[oc]) * 0.25f);
                float vv = b2f(vhat[(size_t)(b * 64 + oc) * HW + px]);
                resh[(size_t)(b * 64 + oc) * HW + px] = f2b(g * vv);
            }
        }
    } else {
        // ---- attention (R12-proven body: in-reg P + in-reg Q) ----
        short* kt = (short*)smem;                 // 16*64*8
        short* vt = (short*)(smem + 16384);       // 8*64*8
        int abid = bid - 512;
        int h = (abid >> 8) & 3, b = abid >> 10;
        int px0b = (abid & 255) * 64;
        const float* K = k2 + (size_t)(b * 4 + h) * 4096;
        const float* V = v2 + (size_t)(b * 4 + h) * 4096;
        bf16* Qbase = qkvg + (size_t)(b * 256 + 192 + h * 16) * HW + px0b;

        {
            int mb = t >> 5, kl = t & 31, q = kl >> 3, s = kl & 7;
            int tile = 2 * mb + (s >> 2), row = q * 4 + (s & 3);
            float4 k0 = *(const float4*)(K + t * 16);
            float4 k1 = *(const float4*)(K + t * 16 + 4);
            float4 kx2 = *(const float4*)(K + t * 16 + 8);
            float4 k3 = *(const float4*)(K + t * 16 + 12);
            short8v lo, hi, zz = {};
            lo[0] = f2bs(k0.x); lo[1] = f2bs(k0.y); lo[2] = f2bs(k0.z); lo[3] = f2bs(k0.w);
            lo[4] = f2bs(k1.x); lo[5] = f2bs(k1.y); lo[6] = f2bs(k1.z); lo[7] = f2bs(k1.w);
            hi[0] = f2bs(kx2.x); hi[1] = f2bs(kx2.y); hi[2] = f2bs(kx2.z); hi[3] = f2bs(kx2.w);
            hi[4] = f2bs(k3.x); hi[5] = f2bs(k3.y); hi[6] = f2bs(k3.z); hi[7] = f2bs(k3.w);
            *(short8v*)&kt[(tile * 64 + row) * 8] = lo;
            *(short8v*)&kt[(tile * 64 + 16 + row) * 8] = hi;
            *(short8v*)&kt[(tile * 64 + 32 + row) * 8] = zz;
            *(short8v*)&kt[(tile * 64 + 48 + row) * 8] = zz;
        }
        #pragma unroll
        for (int u = 0; u < 2; u++) {           // 512 V frags, two per thread
            int f = t * 2 + u;
            int mb = f >> 6, lane = f & 63, quad = lane >> 4, d = lane & 15;
            short8v pk;
            #pragma unroll
            for (int i = 0; i < 8; i++) pk[i] = f2bs(V[(mb * 32 + quad * 8 + i) * 16 + d]);
            *(short8v*)&vt[f * 8] = pk;
        }

        int wave = wuniform(t >> 6);            // 0..3, = this wave's pxt
        int lane = t & 63;
        int quad = lane >> 4, l16 = lane & 15;
        short8v qf = {};
        if (quad < 2) {                         // Q B-frag directly in registers (no LDS)
            int px = wave * 16 + l16;
            #pragma unroll
            for (int i = 0; i < 8; i++)         // 0.25 (= dh^-0.5) * log2(e) folded in
                qf[i] = f2bs(b2f(Qbase[(size_t)(quad * 8 + i) * HW + px]) * 0.36067376022224085f);
        }
        __syncthreads();

        {
            int pxt = wave;
            floatx4 denv = {};
            floatx4 oa = {};
            #pragma unroll
            for (int mb = 0; mb < 8; mb++) {
                short8v kfE = *(const short8v*)&kt[((2 * mb) * 64 + lane) * 8];
                short8v kfO = *(const short8v*)&kt[((2 * mb + 1) * 64 + lane) * 8];
                floatx4 scE = __builtin_amdgcn_mfma_f32_16x16x32_bf16(kfE, qf, (floatx4){0.f, 0.f, 0.f, 0.f}, 0, 0, 0);
                floatx4 scO = __builtin_amdgcn_mfma_f32_16x16x32_bf16(kfO, qf, (floatx4){0.f, 0.f, 0.f, 0.f}, 0, 0, 0);
                floatx4 peE, peO;
                #pragma unroll
                for (int r = 0; r < 4; r++) {
                    peE[r] = exp2f(fminf(scE[r], 86.f));
                    peO[r] = exp2f(fminf(scO[r], 86.f));
                }
                denv += peE;
                denv += peO;
                short8v pa;
                pa[0] = f2bs(peE[0]); pa[1] = f2bs(peE[1]); pa[2] = f2bs(peE[2]); pa[3] = f2bs(peE[3]);
                pa[4] = f2bs(peO[0]); pa[5] = f2bs(peO[1]); pa[6] = f2bs(peO[2]); pa[7] = f2bs(peO[3]);
                short8v vf = *(const short8v*)&vt[(mb * 64 + lane) * 8];
                oa = __builtin_amdgcn_mfma_f32_16x16x32_bf16(vf, pa, oa, 0, 0, 0);
            }
            float den = (denv[0] + denv[1]) + (denv[2] + denv[3]);
            den += __shfl_xor(den, 16, 64);
            den += __shfl_xor(den, 32, 64);
            float rden = 1.f / den;
            #pragma unroll
            for (int r = 0; r < 4; r++)
                Qbase[(size_t)(quad * 4 + r) * HW + pxt * 16 + l16] = f2b(oa[r] * rden);
        }
    }
}

// ---------------- MFMA final proj: [res_h|res_l] -> out fp32. grid (128 px-tiles, 4 b) ---
// B staging conflict-free; Wproj staged fp32->bf16 (R4 path).
__global__ __launch_bounds__(256) void k_proj(const bf16* __restrict__ resh, const bf16* __restrict__ qkvg,
                                              const float* __restrict__ Wproj, const float* __restrict__ bproj,
                                              float* __restrict__ out)
{
    __shared__ short a_s[128 * 128];
    __shared__ short b_s[128 * 128];
    __shared__ float bias_s[128];
    int t = threadIdx.x;
    int b = blockIdx.y;
    int px0 = blockIdx.x * 128;
    const bf16* resl = qkvg + (size_t)(b * 256 + 192) * HW;

    if (t < 128) bias_s[t] = bproj[t];
    #pragma unroll
    for (int i = 0; i < 16; i++) {       // stage A: Wproj fp32 -> bf16
        int idx = i * 1024 + t * 4;
        floatx4 wv = *(const floatx4*)(Wproj + idx);
        short4v pk;
        pk[0] = f2bs(wv[0]); pk[1] = f2bs(wv[1]); pk[2] = f2bs(wv[2]); pk[3] = f2bs(wv[3]);
        *(short4v*)&a_s[idx] = pk;
    }
    {
        int pxs = t & 127, half = t >> 7;
        const short* srcb = half == 0 ? ((const short*)resh + (size_t)b * 64 * HW + px0 + pxs)
                                      : ((const short*)resl + px0 + pxs);
        #pragma unroll
        for (int pp = 0; pp < 8; pp++) {  // stage B: 8-channel gather -> b128 write
            int c0 = half * 64 + pp * 8;
            short8v pk;
            #pragma unroll
            for (int jj = 0; jj < 8; jj++) pk[jj] = srcb[(size_t)(pp * 8 + jj) * HW];
            *(short8v*)&b_s[((c0 >> 3) * 128 + pxs) * 8] = pk;
        }
    }
    __syncthreads();

    int wave = wuniform(t >> 6);
    int lane = t & 63;
    int quad = lane >> 4, l16 = lane & 15;
    floatx4 acc[2][8] = {};
    #pragma unroll
    for (int kk = 0; kk < 4; kk++) {
        short8v a0 = *(const short8v*)&a_s[(wave * 32 + l16) * 128 + kk * 32 + quad * 8];
        short8v a1 = *(const short8v*)&a_s[(wave * 32 + 16 + l16) * 128 + kk * 32 + quad * 8];
        #pragma unroll
        for (int nt = 0; nt < 8; nt++) {
            short8v bv = *(const short8v*)&b_s[((kk * 4 + quad) * 128 + nt * 16 + l16) * 8];
            acc[0][nt] = __builtin_amdgcn_mfma_f32_16x16x32_bf16(a0, bv, acc[0][nt], 0, 0, 0);
            acc[1][nt] = __builtin_amdgcn_mfma_f32_16x16x32_bf16(a1, bv, acc[1][nt], 0, 0, 0);
        }
    }
    #pragma unroll
    for (int m = 0; m < 2; m++) {
        int rowb = wave * 32 + m * 16 + quad * 4;
        #pragma unroll
        for (int nt = 0; nt < 8; nt++) {
            int px = px0 + nt * 16 + l16;
            #pragma unroll
            for (int r = 0; r < 4; r++) {
                int row = rowb + r;
                out[((size_t)b * 128 + row) * HW + px] = acc[m][nt][r] + bias_s[row];
            }
        }
    }
}

extern "C" void kernel_launch(void* const* d_in, const int* in_sizes, int n_in,
                              void* d_out, int out_size, void* d_ws, size_t ws_size,
                              hipStream_t stream)
{
    (void)in_sizes; (void)n_in; (void)out_size; (void)ws_size;
    const float* x     = (const float*)d_in[0];
    const float* Wqkv  = (const float*)d_in[1];
    const float* bqkv  = (const float*)d_in[2];
    const float* Wdw   = (const float*)d_in[3];
    const float* bdw   = (const float*)d_in[4];
    const float* Wa1   = (const float*)d_in[5];
    const float* ba1   = (const float*)d_in[6];
    const float* Wa2   = (const float*)d_in[7];
    const float* ba2   = (const float*)d_in[8];
    const float* Wq    = (const float*)d_in[9];
    const float* bq    = (const float*)d_in[10];
    const float* Wkv   = (const float*)d_in[11];
    const float* bkv   = (const float*)d_in[12];
    const float* Wproj = (const float*)d_in[13];
    const float* bproj = (const float*)d_in[14];

    char* wsb = (char*)d_ws;
    float* xp   = (float*)(wsb + OFFB_XP);
    float* k2   = (float*)(wsb + OFFB_K2);
    float* v2   = (float*)(wsb + OFFB_V2);
    bf16*  qkvg = (bf16*)(wsb + OFFB_QKVG);
    bf16*  resh = (bf16*)(wsb + OFFB_RESH);
    bf16*  p    = (bf16*)d_out;               // scratch in d_out, dead before k_proj
    bf16*  v    = (bf16*)d_out + 4194304;
    float* out  = (float*)d_out;

    k_fuseA<<<dim3(1024), 256, 0, stream>>>(x, Wqkv, bqkv, Wq, bq, qkvg, xp);
    k_fuseB<<<dim3(2560), 256, 0, stream>>>(xp, Wkv, bkv, k2, v2, qkvg, Wdw, bdw, p, v);
    k_fuseC<<<dim3(4608), 256, 0, stream>>>(qkvg, k2, v2, p, v, Wa1, ba1, Wa2, ba2, resh);
    k_proj<<<dim3(128, 4), 256, 0, stream>>>(resh, qkvg, Wproj, bproj, out);
}

// Round 14
// 190.873 us; speedup vs baseline: 1.0527x; 1.0128x over previous
//
#include <hip/hip_runtime.h>
#include <hip/hip_bf16.h>

typedef __hip_bfloat16 bf16;
typedef short short8v __attribute__((ext_vector_type(8)));
typedef short short4v __attribute__((ext_vector_type(4)));
typedef float floatx4 __attribute__((ext_vector_type(4)));

#define HW 16384

__device__ __forceinline__ float b2f(bf16 v) { return __bfloat162float(v); }
__device__ __forceinline__ bf16 f2b(float v) { return __float2bfloat16(v); }
__device__ __forceinline__ short f2bs(float v) { bf16 h = __float2bfloat16(v); return __builtin_bit_cast(short, h); }
__device__ __forceinline__ float bs2f(short s) { return b2f(__builtin_bit_cast(bf16, s)); }
__device__ __forceinline__ int wuniform(int v) { return __builtin_amdgcn_readfirstlane(v); }

// ---- ws byte offsets (total 41 MiB, proven safe) ----
// xp is 512 KB: [0, 524288). NOTHING else below OFFB_K2 (R6 lesson: alias -> NaN).
// R14: k2/v2 fp32 replaced by kbf/vbf -- bf16 K/V PRE-ARRANGED in the attn LDS fragment
// layout (producer-side convert+permute; was re-converted 256x per (b,h) by attn blocks).
#define OFFB_XP    0u
#define OFFB_KBF   524288u            // 128 KB: 16 (b,h) x 4096 shorts (16 tiles x 32 rows x 8)
#define OFFB_VBF   786432u            // 128 KB: 16 (b,h) x 4096 shorts (512 frags x 8)
#define OFFB_QKVG  (1u << 20)         // bf16 (b,256,HW): 0-63 q, 64-127 k, 128-191 v, 192-255 qg->res_l
#define OFFB_RESH  (33u << 20)        // bf16 (b,64,HW)
// p / v-hat scratch in d_out [0,16MiB); d_out fully overwritten by k_proj.

// ======== Launch A: conv1x1 (blocks 0..511) + 8x8 avgpool (blocks 512..1023) ============
// Independent: both read only x; write qkvg / xp respectively.
__global__ __launch_bounds__(256) void k_fuseA(const float* __restrict__ x,
                                               const float* __restrict__ Wqkv, const float* __restrict__ bqkv,
                                               const float* __restrict__ Wq,  const float* __restrict__ bq,
                                               bf16* __restrict__ qkvg, float* __restrict__ xp)
{
    __shared__ __align__(16) char smem[66560];   // conv: a_s 32K | b_s 32K | bias 1K
    int t = threadIdx.x;
    int bid = blockIdx.x;

    if (bid < 512) {
        // ---- conv1x1: x -> qkvg. R12 body (B staged once, my-loop restages A) ----
        short* a_s = (short*)smem;
        short* b_s = (short*)(smem + 32768);
        float* bias_s = (float*)(smem + 65536);
        int b = bid >> 7;
        int px0 = (bid & 127) * 128;

        bias_s[t] = (t < 192) ? bqkv[t] : bq[t - 192];

        int wave = wuniform(t >> 6);
        int lane = t & 63;
        int quad = lane >> 4, l16 = lane & 15;
        int pxs = t & 127, chalf = (t >> 7) * 64;

        {   // stage B once: 8 coalesced loads -> 1 b128 write per 8-ch group
            const float* xb = x + (size_t)b * 128 * HW + px0 + pxs;
            #pragma unroll
            for (int p = 0; p < 8; p++) {
                int c0 = chalf + p * 8;
                float xv[8];
                #pragma unroll
                for (int jj = 0; jj < 8; jj++) xv[jj] = xb[(size_t)(c0 + jj) * HW];
                short8v pk;
                #pragma unroll
                for (int jj = 0; jj < 8; jj++) pk[jj] = f2bs(xv[jj]);
                *(short8v*)&b_s[((c0 >> 3) * 128 + pxs) * 8] = pk;
            }
        }

        #pragma unroll 1
        for (int my = 0; my < 2; my++) {
            __syncthreads();                  // my=1: mfma reads of a_s done
            #pragma unroll
            for (int i = 0; i < 16; i++) {    // stage A(my): fp32 -> bf16 (R4-proven path)
                int idx = i * 1024 + t * 4;
                int row = idx >> 7, col = idx & 127;
                int oc = my * 128 + row;
                const float* srcw = (oc < 192) ? (Wqkv + oc * 128 + col) : (Wq + (oc - 192) * 128 + col);
                floatx4 wv = *(const floatx4*)srcw;
                short4v pk4;
                pk4[0] = f2bs(wv[0]); pk4[1] = f2bs(wv[1]); pk4[2] = f2bs(wv[2]); pk4[3] = f2bs(wv[3]);
                *(short4v*)&a_s[row * 128 + col] = pk4;
            }
            __syncthreads();                  // a_s (and b_s on my=0) visible

            floatx4 acc[2][8] = {};
            #pragma unroll
            for (int kk = 0; kk < 4; kk++) {
                short8v a0 = *(const short8v*)&a_s[(wave * 32 + l16) * 128 + kk * 32 + quad * 8];
                short8v a1 = *(const short8v*)&a_s[(wave * 32 + 16 + l16) * 128 + kk * 32 + quad * 8];
                #pragma unroll
                for (int nt = 0; nt < 8; nt++) {
                    short8v bv = *(const short8v*)&b_s[((kk * 4 + quad) * 128 + nt * 16 + l16) * 8];
                    acc[0][nt] = __builtin_amdgcn_mfma_f32_16x16x32_bf16(a0, bv, acc[0][nt], 0, 0, 0);
                    acc[1][nt] = __builtin_amdgcn_mfma_f32_16x16x32_bf16(a1, bv, acc[1][nt], 0, 0, 0);
                }
            }
            #pragma unroll
            for (int m = 0; m < 2; m++) {
                int rowb = wave * 32 + m * 16 + quad * 4;
                #pragma unroll
                for (int nt = 0; nt < 8; nt++) {
                    int px = px0 + nt * 16 + l16;
                    #pragma unroll
                    for (int r = 0; r < 4; r++) {
                        int row = rowb + r;
                        float val = acc[m][nt][r] + bias_s[my * 128 + row];
                        qkvg[((size_t)b * 256 + my * 128 + row) * HW + px] = f2b(val);
                    }
                }
            }
        }
    } else {
        // ---- 8x8 avgpool: x -> xp ----
        int idx = (bid - 512) * 256 + t;
        int j = idx & 15, i = (idx >> 4) & 15, bc = idx >> 8;
        const float* src = x + (size_t)bc * HW + (i * 8) * 128 + j * 8;
        float s = 0.f;
        #pragma unroll
        for (int u = 0; u < 8; u++) {
            #pragma unroll
            for (int t2 = 0; t2 < 8; t2++) s += src[u * 128 + t2];
        }
        xp[bc * 256 + i * 16 + j] = s * (1.f / 64.f);
    }
}

// ======== Launch B: kv conv (blocks 0..511) + depthwise 3x3 (blocks 512..2559) ==========
// kv reads xp -> kbf/vbf (bf16, pre-arranged in attn fragment layout); dw reads qkvg -> p/v.
__global__ __launch_bounds__(256) void k_fuseB(const float* __restrict__ xp,
                                               const float* __restrict__ Wkv, const float* __restrict__ bkv,
                                               short* __restrict__ kbf, short* __restrict__ vbf,
                                               const bf16* __restrict__ qkvg,
                                               const float* __restrict__ Wdw, const float* __restrict__ bdw,
                                               bf16* __restrict__ p, bf16* __restrict__ v)
{
    __shared__ float w_s[128];
    int t = threadIdx.x;
    int bid = blockIdx.x;

    if (bid < 512) {
        // ---- kv conv (R7-proven): one (b,o) per block; bf16 write in fragment layout ----
        int o = bid & 127, b = bid >> 7;
        int m = t;
        if (m < 128) w_s[m] = Wkv[o * 128 + m];
        __syncthreads();
        const float* xb = xp + b * 32768 + m;
        float s0 = 0.f, s1 = 0.f, s2 = 0.f, s3 = 0.f;
        #pragma unroll
        for (int c = 0; c < 128; c += 4) {
            s0 += w_s[c]     * xb[(size_t)(c)     * 256];
            s1 += w_s[c + 1] * xb[(size_t)(c + 1) * 256];
            s2 += w_s[c + 2] * xb[(size_t)(c + 2) * 256];
            s3 += w_s[c + 3] * xb[(size_t)(c + 3) * 256];
        }
        float a = bkv[o] + ((s0 + s1) + (s2 + s3));
        short av = f2bs(a);                  // same rounding as attn previously applied
        int sb = o >> 6, r = o & 63, gh = r >> 4, dh = r & 15;
        if (sb == 0) {
            // K: key-permuted A-frag slot (kl -> tile 2mb+(s>>2), row q*4+(s&3))
            int mb = m >> 5, kl = m & 31, q = kl >> 3, s = kl & 7;
            int tile = 2 * mb + (s >> 2), row = q * 4 + (s & 3);
            int rr = (dh < 8) ? row : 16 + row;
            kbf[(size_t)(b * 4 + gh) * 4096 + (tile * 32 + rr) * 8 + (dh & 7)] = av;
        } else {
            // V: B-frag slot (frag f = mb*64 + quad*16 + d, elem i)
            int mb = m >> 5, rem = m & 31, quad = rem >> 3, i = rem & 7;
            int f = mb * 64 + quad * 16 + dh;
            vbf[(size_t)(b * 4 + gh) * 4096 + f * 8 + i] = av;
        }
    } else {
        // ---- depthwise 3x3 + q*k (proven body), blk = bid-512 ----
        int blk = bid - 512;
        int bc = blk >> 3;
        int c = bc & 63, b = bc >> 6;
        int g = (blk & 7) * 256 + t;
        int i = g >> 4;
        int j0 = (g & 15) * 8;
        float acc[3][8];
        #pragma unroll
        for (int pl = 0; pl < 3; pl++) {
            float bias = bdw[pl * 64 + c];
            #pragma unroll
            for (int t2 = 0; t2 < 8; t2++) acc[pl][t2] = bias;
        }
        #pragma unroll
        for (int pl = 0; pl < 3; pl++) {
            const bf16* plane = qkvg + (size_t)(b * 256 + pl * 64 + c) * HW;
            const float* w = Wdw + (pl * 64 + c) * 9;
            #pragma unroll
            for (int dy = 0; dy < 3; dy++) {
                int ii = i + dy - 1;
                float e[10];
                if ((unsigned)ii < 128u) {
                    const bf16* r = plane + ii * 128 + j0;
                    short8v v8 = *(const short8v*)r;
                    #pragma unroll
                    for (int t2 = 0; t2 < 8; t2++) e[t2 + 1] = bs2f(v8[t2]);
                    e[0] = (j0 > 0) ? b2f(r[-1]) : 0.f;
                    e[9] = (j0 < 120) ? b2f(r[8]) : 0.f;
                } else {
                    #pragma unroll
                    for (int t2 = 0; t2 < 10; t2++) e[t2] = 0.f;
                }
                float wa = w[dy * 3], wb = w[dy * 3 + 1], wc = w[dy * 3 + 2];
                #pragma unroll
                for (int t2 = 0; t2 < 8; t2++)
                    acc[pl][t2] += wa * e[t2] + wb * e[t2 + 1] + wc * e[t2 + 2];
            }
        }
        short8v pv, vv;
        #pragma unroll
        for (int t2 = 0; t2 < 8; t2++) {
            pv[t2] = f2bs(acc[0][t2] * acc[1][t2]);
            vv[t2] = f2bs(acc[2][t2]);
        }
        size_t off = (size_t)(b * 64 + c) * HW + i * 128 + j0;
        *(short8v*)(p + off) = pv;
        *(short8v*)(v + off) = vv;
    }
}

// ======== Launch C: high-freq gate (blocks 0..511) + attention (blocks 512..4607) =======
// attn K/V staging is now a pure linear bf16 copy (conversion+permute done in fuseB).
__global__ __launch_bounds__(256) void k_fuseC(bf16* __restrict__ qkvg,
                                               const short* __restrict__ kbf, const short* __restrict__ vbf,
                                               const bf16* __restrict__ p, const bf16* __restrict__ vhat,
                                               const float* __restrict__ Wa1, const float* __restrict__ ba1,
                                               const float* __restrict__ Wa2, const float* __restrict__ ba2,
                                               bf16* __restrict__ resh)
{
    __shared__ __align__(16) char smem[49664];  // resh: 48.5K | attn: 24K
    int t = threadIdx.x;
    int bid = blockIdx.x;

    if (bid < 512) {
        // ---- high-freq gate (proven body; Wa staged fp32->bf16, R4 path) ----
        short* aw1 = (short*)smem;                    // 64*64
        short* aw2 = (short*)(smem + 8192);           // 64*64
        short* bp  = (short*)(smem + 16384);          // 8*128*8
        short* bs2 = (short*)(smem + 32768);          // 8*128*8
        float* b1s = (float*)(smem + 49152);          // 64
        float* b2s = (float*)(smem + 49408);          // 64
        int b = bid >> 7;
        int px0 = (bid & 127) * 128;

        if (t < 64) { b1s[t] = ba1[t]; b2s[t] = ba2[t]; }
        #pragma unroll
        for (int i = 0; i < 4; i++) {        // stage Wa1/Wa2 fp32->bf16 (4096 each)
            int idx = i * 1024 + t * 4;
            floatx4 w1 = *(const floatx4*)(Wa1 + idx);
            floatx4 w2 = *(const floatx4*)(Wa2 + idx);
            short4v p1, p2;
            #pragma unroll
            for (int e = 0; e < 4; e++) { p1[e] = f2bs(w1[e]); p2[e] = f2bs(w2[e]); }
            *(short4v*)&aw1[idx] = p1;
            *(short4v*)&aw2[idx] = p2;
        }
        {
            int pxs = t & 127, chalf = (t >> 7) * 32;
            const short* pb = (const short*)p + (size_t)b * 64 * HW + px0 + pxs;
            #pragma unroll
            for (int pp = 0; pp < 4; pp++) {  // stage P: 8-channel gather -> b128 write
                int c0 = chalf + pp * 8;
                short8v pk;
                #pragma unroll
                for (int jj = 0; jj < 8; jj++) pk[jj] = pb[(size_t)(c0 + jj) * HW];
                *(short8v*)&bp[((c0 >> 3) * 128 + pxs) * 8] = pk;
            }
        }
        __syncthreads();

        int wave = wuniform(t >> 6);
        int lane = t & 63;
        int quad = lane >> 4, l16 = lane & 15;
        int k0 = wave * 16 + quad * 4;

        floatx4 acc1[8] = {};
        #pragma unroll
        for (int kk = 0; kk < 2; kk++) {
            short8v af = *(const short8v*)&aw1[(wave * 16 + l16) * 64 + kk * 32 + quad * 8];
            #pragma unroll
            for (int nt = 0; nt < 8; nt++) {
                short8v bf = *(const short8v*)&bp[((kk * 4 + quad) * 128 + nt * 16 + l16) * 8];
                acc1[nt] = __builtin_amdgcn_mfma_f32_16x16x32_bf16(af, bf, acc1[nt], 0, 0, 0);
            }
        }
        #pragma unroll
        for (int nt = 0; nt < 8; nt++) {     // swish + repack C-layout -> B-frag layout
            int px = nt * 16 + l16;
            short4v pk;
            #pragma unroll
            for (int r = 0; r < 4; r++) {
                float a = acc1[nt][r] + b1s[k0 + r];
                pk[r] = f2bs(a / (1.f + __expf(-a)));
            }
            *(short4v*)&bs2[((k0 >> 3) * 128 + px) * 8 + (k0 & 7)] = pk;
        }
        __syncthreads();

        floatx4 acc2[8] = {};
        #pragma unroll
        for (int kk = 0; kk < 2; kk++) {
            short8v af = *(const short8v*)&aw2[(wave * 16 + l16) * 64 + kk * 32 + quad * 8];
            #pragma unroll
            for (int nt = 0; nt < 8; nt++) {
                short8v bf = *(const short8v*)&bs2[((kk * 4 + quad) * 128 + nt * 16 + l16) * 8];
                acc2[nt] = __builtin_amdgcn_mfma_f32_16x16x32_bf16(af, bf, acc2[nt], 0, 0, 0);
            }
        }
        #pragma unroll
        for (int nt = 0; nt < 8; nt++) {
            int px = px0 + nt * 16 + l16;
            #pragma unroll
            for (int r = 0; r < 4; r++) {
                int oc = k0 + r;
                float g = tanhf((acc2[nt][r] + b2s[oc]) * 0.25f);
                float vv = b2f(vhat[(size_t)(b * 64 + oc) * HW + px]);
                resh[(size_t)(b * 64 + oc) * HW + px] = f2b(g * vv);
            }
        }
    } else {
        // ---- attention (R12 body; K/V staging = linear bf16 copy) ----
        short* kt = (short*)smem;                 // 16*64*8
        short* vt = (short*)(smem + 16384);       // 8*64*8
        int abid = bid - 512;
        int h = (abid >> 8) & 3, b = abid >> 10;
        int px0b = (abid & 255) * 64;
        const short* Kb = kbf + (size_t)(b * 4 + h) * 4096;
        const short* Vb = vbf + (size_t)(b * 4 + h) * 4096;
        bf16* Qbase = qkvg + (size_t)(b * 256 + 192 + h * 16) * HW + px0b;

        #pragma unroll
        for (int u = 0; u < 2; u++) {           // K: linear copy of 512 data rows
            int f = t * 2 + u;
            int tile = f >> 5, rr = f & 31;
            *(short8v*)&kt[(tile * 64 + rr) * 8] = *(const short8v*)&Kb[f * 8];
            *(short8v*)&kt[(tile * 64 + 32 + rr) * 8] = (short8v){};   // zero rows 32..63
        }
        #pragma unroll
        for (int u = 0; u < 2; u++) {           // V: linear copy of 512 frags
            int f = t * 2 + u;
            *(short8v*)&vt[f * 8] = *(const short8v*)&Vb[f * 8];
        }

        int wave = wuniform(t >> 6);            // 0..3, = this wave's pxt
        int lane = t & 63;
        int quad = lane >> 4, l16 = lane & 15;
        short8v qf = {};
        if (quad < 2) {                         // Q B-frag directly in registers (no LDS)
            int px = wave * 16 + l16;
            #pragma unroll
            for (int i = 0; i < 8; i++)         // 0.25 (= dh^-0.5) * log2(e) folded in
                qf[i] = f2bs(b2f(Qbase[(size_t)(quad * 8 + i) * HW + px]) * 0.36067376022224085f);
        }
        __syncthreads();

        {
            int pxt = wave;
            floatx4 denv = {};
            floatx4 oa = {};
            #pragma unroll
            for (int mb = 0; mb < 8; mb++) {
                short8v kfE = *(const short8v*)&kt[((2 * mb) * 64 + lane) * 8];
                short8v kfO = *(const short8v*)&kt[((2 * mb + 1) * 64 + lane) * 8];
                floatx4 scE = __builtin_amdgcn_mfma_f32_16x16x32_bf16(kfE, qf, (floatx4){0.f, 0.f, 0.f, 0.f}, 0, 0, 0);
                floatx4 scO = __builtin_amdgcn_mfma_f32_16x16x32_bf16(kfO, qf, (floatx4){0.f, 0.f, 0.f, 0.f}, 0, 0, 0);
                floatx4 peE, peO;
                #pragma unroll
                for (int r = 0; r < 4; r++) {
                    peE[r] = exp2f(fminf(scE[r], 86.f));
                    peO[r] = exp2f(fminf(scO[r], 86.f));
                }
                denv += peE;
                denv += peO;
                short8v pa;
                pa[0] = f2bs(peE[0]); pa[1] = f2bs(peE[1]); pa[2] = f2bs(peE[2]); pa[3] = f2bs(peE[3]);
                pa[4] = f2bs(peO[0]); pa[5] = f2bs(peO[1]); pa[6] = f2bs(peO[2]); pa[7] = f2bs(peO[3]);
                short8v vf = *(const short8v*)&vt[(mb * 64 + lane) * 8];
                oa = __builtin_amdgcn_mfma_f32_16x16x32_bf16(vf, pa, oa, 0, 0, 0);
            }
            float den = (denv[0] + denv[1]) + (denv[2] + denv[3]);
            den += __shfl_xor(den, 16, 64);
            den += __shfl_xor(den, 32, 64);
            float rden = 1.f / den;
            #pragma unroll
            for (int r = 0; r < 4; r++)
                Qbase[(size_t)(quad * 4 + r) * HW + pxt * 16 + l16] = f2b(oa[r] * rden);
        }
    }
}

// ---------------- MFMA final proj: [res_h|res_l] -> out fp32. grid (128 px-tiles, 4 b) ---
// B staging conflict-free; Wproj staged fp32->bf16 (R4 path).
__global__ __launch_bounds__(256) void k_proj(const bf16* __restrict__ resh, const bf16* __restrict__ qkvg,
                                              const float* __restrict__ Wproj, const float* __restrict__ bproj,
                                              float* __restrict__ out)
{
    __shared__ short a_s[128 * 128];
    __shared__ short b_s[128 * 128];
    __shared__ float bias_s[128];
    int t = threadIdx.x;
    int b = blockIdx.y;
    int px0 = blockIdx.x * 128;
    const bf16* resl = qkvg + (size_t)(b * 256 + 192) * HW;

    if (t < 128) bias_s[t] = bproj[t];
    #pragma unroll
    for (int i = 0; i < 16; i++) {       // stage A: Wproj fp32 -> bf16
        int idx = i * 1024 + t * 4;
        floatx4 wv = *(const floatx4*)(Wproj + idx);
        short4v pk;
        pk[0] = f2bs(wv[0]); pk[1] = f2bs(wv[1]); pk[2] = f2bs(wv[2]); pk[3] = f2bs(wv[3]);
        *(short4v*)&a_s[idx] = pk;
    }
    {
        int pxs = t & 127, half = t >> 7;
        const short* srcb = half == 0 ? ((const short*)resh + (size_t)b * 64 * HW + px0 + pxs)
                                      : ((const short*)resl + px0 + pxs);
        #pragma unroll
        for (int pp = 0; pp < 8; pp++) {  // stage B: 8-channel gather -> b128 write
            int c0 = half * 64 + pp * 8;
            short8v pk;
            #pragma unroll
            for (int jj = 0; jj < 8; jj++) pk[jj] = srcb[(size_t)(pp * 8 + jj) * HW];
            *(short8v*)&b_s[((c0 >> 3) * 128 + pxs) * 8] = pk;
        }
    }
    __syncthreads();

    int wave = wuniform(t >> 6);
    int lane = t & 63;
    int quad = lane >> 4, l16 = lane & 15;
    floatx4 acc[2][8] = {};
    #pragma unroll
    for (int kk = 0; kk < 4; kk++) {
        short8v a0 = *(const short8v*)&a_s[(wave * 32 + l16) * 128 + kk * 32 + quad * 8];
        short8v a1 = *(const short8v*)&a_s[(wave * 32 + 16 + l16) * 128 + kk * 32 + quad * 8];
        #pragma unroll
        for (int nt = 0; nt < 8; nt++) {
            short8v bv = *(const short8v*)&b_s[((kk * 4 + quad) * 128 + nt * 16 + l16) * 8];
            acc[0][nt] = __builtin_amdgcn_mfma_f32_16x16x32_bf16(a0, bv, acc[0][nt], 0, 0, 0);
            acc[1][nt] = __builtin_amdgcn_mfma_f32_16x16x32_bf16(a1, bv, acc[1][nt], 0, 0, 0);
        }
    }
    #pragma unroll
    for (int m = 0; m < 2; m++) {
        int rowb = wave * 32 + m * 16 + quad * 4;
        #pragma unroll
        for (int nt = 0; nt < 8; nt++) {
            int px = px0 + nt * 16 + l16;
            #pragma unroll
            for (int r = 0; r < 4; r++) {
                int row = rowb + r;
                out[((size_t)b * 128 + row) * HW + px] = acc[m][nt][r] + bias_s[row];
            }
        }
    }
}

extern "C" void kernel_launch(void* const* d_in, const int* in_sizes, int n_in,
                              void* d_out, int out_size, void* d_ws, size_t ws_size,
                              hipStream_t stream)
{
    (void)in_sizes; (void)n_in; (void)out_size; (void)ws_size;
    const float* x     = (const float*)d_in[0];
    const float* Wqkv  = (const float*)d_in[1];
    const float* bqkv  = (const float*)d_in[2];
    const float* Wdw   = (const float*)d_in[3];
    const float* bdw   = (const float*)d_in[4];
    const float* Wa1   = (const float*)d_in[5];
    const float* ba1   = (const float*)d_in[6];
    const float* Wa2   = (const float*)d_in[7];
    const float* ba2   = (const float*)d_in[8];
    const float* Wq    = (const float*)d_in[9];
    const float* bq    = (const float*)d_in[10];
    const float* Wkv   = (const float*)d_in[11];
    const float* bkv   = (const float*)d_in[12];
    const float* Wproj = (const float*)d_in[13];
    const float* bproj = (const float*)d_in[14];

    char* wsb = (char*)d_ws;
    float* xp   = (float*)(wsb + OFFB_XP);
    short* kbf  = (short*)(wsb + OFFB_KBF);
    short* vbf  = (short*)(wsb + OFFB_VBF);
    bf16*  qkvg = (bf16*)(wsb + OFFB_QKVG);
    bf16*  resh = (bf16*)(wsb + OFFB_RESH);
    bf16*  p    = (bf16*)d_out;               // scratch in d_out, dead before k_proj
    bf16*  v    = (bf16*)d_out + 4194304;
    float* out  = (float*)d_out;

    k_fuseA<<<dim3(1024), 256, 0, stream>>>(x, Wqkv, bqkv, Wq, bq, qkvg, xp);
    k_fuseB<<<dim3(2560), 256, 0, stream>>>(xp, Wkv, bkv, kbf, vbf, qkvg, Wdw, bdw, p, v);
    k_fuseC<<<dim3(4608), 256, 0, stream>>>(qkvg, kbf, vbf, p, v, Wa1, ba1, Wa2, ba2, resh);
    k_proj<<<dim3(128, 4), 256, 0, stream>>>(resh, qkvg, Wproj, bproj, out);
}